// Round 1
// baseline (176.935 us; speedup 1.0000x reference)
//
#include <hip/hip_runtime.h>
#include <math.h>

#define NCAM 6
#define C_CH 64
#define HF   64
#define WF   176
#define GDIM 129
#define NY   4
#define NH   3
#define DD   128
#define WDIM 128
#define NP   (DD*WDIM)

struct alignas(16) BoxP {
    int   x0L, x0R, y0T, y0B;
    float wxL, wxR, wyT, wyB;
    float area; float pad0, pad1, pad2;
};
static_assert(sizeof(BoxP) == 48, "BoxP size");

// ---------------- Kernel 1: project grid corners to normalized coords ----------------
__global__ void k_project(const float* __restrict__ ks,
                          const float* __restrict__ imu2cs,
                          const float* __restrict__ post_rots,
                          const float* __restrict__ post_trans,
                          const float* __restrict__ undists,
                          const float* __restrict__ grid,
                          float2* __restrict__ ncbuf)
{
    const int n   = blockIdx.y;
    const int idx = blockIdx.x * blockDim.x + threadIdx.x;
    const int per = NY * GDIM * GDIM;
    if (idx >= per) return;
    const int ny  = idx / (GDIM * GDIM);
    const int rem = idx % (GDIM * GDIM);
    const int gz  = rem / GDIM;
    const int gx  = rem % GDIM;

    const float* k  = ks         + n * 9;
    const float* m  = imu2cs     + n * 12;
    const float* pr = post_rots  + n * 9;
    const float* pt = post_trans + n * 3;
    const float* D  = undists    + n * 7;

    // calib = k @ imu2c   ([3,3] @ [3,4])
    float cal[12];
    #pragma unroll
    for (int i = 0; i < 3; ++i)
        #pragma unroll
        for (int j = 0; j < 4; ++j)
            cal[i*4+j] = k[i*3+0]*m[0*4+j] + k[i*3+1]*m[1*4+j] + k[i*3+2]*m[2*4+j];

    const float vx = grid[(gz*GDIM + gx)*3 + 0];
    const float vy = 2.0f - (float)ny;               // ys = -arange(0,4)+2
    const float vz = grid[(gz*GDIM + gx)*3 + 2];

    const float hx = cal[0]*vx + cal[1]*vy + cal[2]*vz  + cal[3];
    const float hy = cal[4]*vx + cal[5]*vy + cal[6]*vz  + cal[7];
    const float hz = cal[8]*vx + cal[9]*vy + cal[10]*vz + cal[11];

    const float fl = (hz > 0.0f) ? 1.0f : 0.0f;      // flag (x,y zeroed behind camera)
    const float px = (hx * fl) / hz;
    const float py = (hy * fl) / hz;

    const float fx = k[0], fy = k[4], cx = k[2], cy = k[5];
    const float x = (px - cx) / fx;
    const float y = (py - cy) / fy;

    float xd, yd;
    if (D[6] == 1.0f) {
        // fisheye
        const float r  = sqrtf(x*x + y*y);
        const float th = atanf(r);
        const float t2 = th * th;
        const float t4 = t2 * t2;
        const float rad = th * (1.0f + D[0]*t2 + D[1]*t4 + D[2]*(t2*t4) + D[5]*(t4*t4)) / r;
        xd = x * rad * fx + cx;
        yd = y * rad * fy + cy;
    } else {
        // pinhole
        const float k1 = D[0], k2 = D[1], k3 = D[2], p1 = D[3], p2 = D[4];
        const float r2 = x*x + y*y;
        const float poly = 1.0f + k1*r2 + k2*r2*r2 + k3*r2*r2*r2;
        const float xdd = x*poly + (2.0f*p1*x*y + p2*(r2 + 2.0f*x*x));
        const float ydd = y*poly + (p1*(r2 + 2.0f*y*y) + 2.0f*p2*x*y);
        xd = xdd * fx + cx;
        yd = ydd * fy + cy;
    }
    xd *= fl; yd *= fl;

    const float qx = pr[0]*xd + pr[1]*yd + pt[0];
    const float qy = pr[3]*xd + pr[4]*yd + pt[1];
    const float ncx = fminf(fmaxf(2.0f*qx - 1.0f, -1.0f), 1.0f);
    const float ncy = fminf(fmaxf(2.0f*qy - 1.0f, -1.0f), 1.0f);
    ncbuf[((n*NY + ny)*GDIM + gz)*GDIM + gx] = make_float2(ncx, ncy);
}

// ---------------- Kernel 2a: row cumsum (axis=-1) + transpose to channel-last ----------------
// Block per (n,h). LDS tile [w][c] padded to stride 65 for bank-conflict freedom.
__global__ __launch_bounds__(256) void k_rowcum(const float* __restrict__ feat,
                                                float* __restrict__ integ)
{
    __shared__ float lds[WF * 65];
    const int h   = blockIdx.x;
    const int n   = blockIdx.y;
    const int tid = threadIdx.x;

    for (int idx = tid; idx < C_CH * WF; idx += 256) {
        const int c = idx / WF;
        const int w = idx % WF;
        lds[w*65 + c] = feat[((size_t)(n*C_CH + c)*HF + h)*WF + w];
    }
    __syncthreads();
    if (tid < C_CH) {
        float run = 0.0f;
        for (int w = 0; w < WF; ++w) {
            run += lds[w*65 + tid];
            lds[w*65 + tid] = run;
        }
    }
    __syncthreads();
    float* outp = integ + (size_t)(n*HF + h) * (WF * C_CH);
    for (int idx = tid; idx < WF * C_CH; idx += 256) {
        const int w = idx / C_CH;
        const int c = idx % C_CH;
        outp[idx] = lds[w*65 + c];   // [n][h][w][c], fully coalesced
    }
}

// ---------------- Kernel 2b: column cumsum (axis=-2), in place, channel-last ----------------
__global__ void k_colcum(float* __restrict__ integ)
{
    const int t = blockIdx.x * blockDim.x + threadIdx.x;
    const int n = blockIdx.y;
    if (t >= WF * C_CH) return;
    float* p = integ + (size_t)n * HF * WF * C_CH + t;
    float run = 0.0f;
    for (int h = 0; h < HF; ++h) {
        run += p[(size_t)h * (WF * C_CH)];
        p[(size_t)h * (WF * C_CH)] = run;
    }
}

// ---------------- Kernel 3: bbox + bilinear params per (cam, nh, p) ----------------
__global__ void k_boxparams(const float2* __restrict__ ncbuf, BoxP* __restrict__ bp)
{
    const int idx = blockIdx.x * blockDim.x + threadIdx.x;
    if (idx >= NCAM * NH * NP) return;
    const int n  = idx / (NH * NP);
    const int r  = idx % (NH * NP);
    const int nh = r / NP;
    const int p  = r % NP;
    const int d  = p / WDIM;
    const int wd = p % WDIM;

    float left = 1e30f, right = -1e30f, top = 1e30f, bot = -1e30f;
    #pragma unroll
    for (int a = 0; a < 2; ++a)
        #pragma unroll
        for (int b = 0; b < 2; ++b)
            #pragma unroll
            for (int cc = 0; cc < 2; ++cc) {
                const float2 v = ncbuf[((n*NY + nh + a)*GDIM + d + b)*GDIM + wd + cc];
                left  = fminf(left,  v.x);  right = fmaxf(right, v.x);
                top   = fminf(top,   v.y);  bot   = fmaxf(bot,   v.y);
            }

    // area = (r-l)*(b-t)*Hf*Wf*0.25 + EPS  (mirror reference op order)
    const float area = (right - left) * (bot - top) * (float)HF * (float)WF * 0.25f + 1e-6f;

    const float xLp = fminf(fmaxf((left  + 1.0f) * 0.5f * (float)(WF-1), 0.0f), (float)(WF-1));
    const float xRp = fminf(fmaxf((right + 1.0f) * 0.5f * (float)(WF-1), 0.0f), (float)(WF-1));
    const float yTp = fminf(fmaxf((top   + 1.0f) * 0.5f * (float)(HF-1), 0.0f), (float)(HF-1));
    const float yBp = fminf(fmaxf((bot   + 1.0f) * 0.5f * (float)(HF-1), 0.0f), (float)(HF-1));
    const float xL0 = floorf(xLp), xR0 = floorf(xRp), yT0 = floorf(yTp), yB0 = floorf(yBp);

    BoxP o;
    o.x0L = (int)xL0; o.x0R = (int)xR0; o.y0T = (int)yT0; o.y0B = (int)yB0;
    o.wxL = xLp - xL0; o.wxR = xRp - xR0; o.wyT = yTp - yT0; o.wyB = yBp - yB0;
    o.area = area; o.pad0 = 0.0f; o.pad1 = 0.0f; o.pad2 = 0.0f;
    bp[idx] = o;
}

// ---------------- Kernel 4: sample integral image, combine, max over cameras ----------------
// Block = 256 threads (4 waves). Each wave handles one (nh, p) at a time, lane = channel.
// Integral image is channel-last, so the 16 gathers/camera are coalesced 256B loads.
__global__ __launch_bounds__(256) void k_sample(const float* __restrict__ integ,
                                                const BoxP* __restrict__ bp,
                                                float* __restrict__ out)
{
    __shared__ float sm[C_CH][17];   // stride 17: conflict-free transpose
    const int nh   = blockIdx.y;
    const int p0   = blockIdx.x * 16;
    const int tid  = threadIdx.x;
    const int wave = tid >> 6;
    const int c    = tid & 63;

    #pragma unroll 1
    for (int j = 0; j < 4; ++j) {
        const int pj = p0 + wave*4 + j;
        float vmax = -3.402823466e38f;
        #pragma unroll 1
        for (int n = 0; n < NCAM; ++n) {
            const BoxP b = bp[(n*NH + nh)*NP + pj];
            const float* ib = integ + (size_t)n * (HF*WF*C_CH) + c;
            const int xL0 = b.x0L, xR0 = b.x0R, yT0 = b.y0T, yB0 = b.y0B;
            const int xL1 = min(xL0 + 1, WF-1), xR1 = min(xR0 + 1, WF-1);
            const int yT1 = min(yT0 + 1, HF-1), yB1 = min(yB0 + 1, HF-1);

            auto L = [&](int y, int x) -> float { return ib[(size_t)(y*WF + x) * C_CH]; };
            auto S = [&](int y0, int y1, float wy, int x0, int x1, float wx) -> float {
                const float v00 = L(y0, x0), v01 = L(y0, x1);
                const float v10 = L(y1, x0), v11 = L(y1, x1);
                return v00*(1.0f-wx)*(1.0f-wy) + v01*wx*(1.0f-wy)
                     + v10*(1.0f-wx)*wy        + v11*wx*wy;
            };
            const float tl = S(yT0, yT1, b.wyT, xL0, xL1, b.wxL);
            const float br = S(yB0, yB1, b.wyB, xR0, xR1, b.wxR);
            const float tr = S(yT0, yT1, b.wyT, xR0, xR1, b.wxR);
            const float bl = S(yB0, yB1, b.wyB, xL0, xL1, b.wxL);
            const float s  = tl + br - tr - bl;
            const float val = (b.area > 1e-6f) ? (s / b.area) : 0.0f;
            vmax = fmaxf(vmax, val);
        }
        sm[c][wave*4 + j] = vmax;
    }
    __syncthreads();
    // Coalesced-ish output: each group of 16 lanes writes a 64B-contiguous chunk.
    for (int idx = tid; idx < C_CH * 16; idx += 256) {
        const int cc = idx >> 4;
        const int jj = idx & 15;
        out[(size_t)(cc*NH + nh)*NP + p0 + jj] = sm[cc][jj];
    }
}

extern "C" void kernel_launch(void* const* d_in, const int* in_sizes, int n_in,
                              void* d_out, int out_size, void* d_ws, size_t ws_size,
                              hipStream_t stream)
{
    const float* feats      = (const float*)d_in[0];  // [1,6,64,64,176]
    const float* ks         = (const float*)d_in[1];  // [1,6,3,3]
    const float* imu2cs     = (const float*)d_in[2];  // [1,6,3,4]
    const float* post_rots  = (const float*)d_in[3];  // [1,6,3,3]
    const float* post_trans = (const float*)d_in[4];  // [1,6,3]
    const float* undists    = (const float*)d_in[5];  // [1,6,7]
    const float* grid       = (const float*)d_in[6];  // [1,129,129,3]
    float* out = (float*)d_out;                       // [1,192,128,128]

    char* ws = (char*)d_ws;
    size_t off = 0;
    float2* ncbuf = (float2*)(ws + off);
    off += sizeof(float2) * NCAM * NY * GDIM * GDIM;
    off = (off + 255) & ~(size_t)255;
    float* integ = (float*)(ws + off);
    off += sizeof(float) * NCAM * HF * WF * C_CH;
    off = (off + 255) & ~(size_t)255;
    BoxP* bp = (BoxP*)(ws + off);
    off += sizeof(BoxP) * NCAM * NH * NP;
    (void)ws_size; (void)in_sizes; (void)n_in; (void)out_size;

    dim3 g1((NY*GDIM*GDIM + 255)/256, NCAM);
    k_project<<<g1, 256, 0, stream>>>(ks, imu2cs, post_rots, post_trans, undists, grid, ncbuf);

    dim3 g2a(HF, NCAM);
    k_rowcum<<<g2a, 256, 0, stream>>>(feats, integ);

    dim3 g2b((WF*C_CH + 255)/256, NCAM);
    k_colcum<<<g2b, 256, 0, stream>>>(integ);

    dim3 g3((NCAM*NH*NP + 255)/256);
    k_boxparams<<<g3, 256, 0, stream>>>(ncbuf, bp);

    dim3 g4(NP/16, NH);
    k_sample<<<g4, 256, 0, stream>>>(integ, bp, out);
}

// Round 2
// 160.966 us; speedup vs baseline: 1.0992x; 1.0992x over previous
//
#include <hip/hip_runtime.h>
#include <math.h>

#define NCAM 6
#define C_CH 64
#define HF   64
#define WF   176
#define GDIM 129
#define NY   4
#define NH   3
#define DD   128
#define WDIM 128
#define NP   (DD*WDIM)

// 64-byte BoxP: row/col BYTE offsets into the channel-last integral image,
// lerp weights, and the gated area. One s_load_dwordx16 per (cam,voxel).
struct alignas(64) BoxP {
    int   r0, r1, r2, r3;      // yT0,yT1,yB0,yB1 row byte offsets (y*WF*C_CH*4)
    int   c0, c1, c2, c3;      // xL0,xL1,xR0,xR1 col byte offsets (x*C_CH*4)
    float wxL, wxR, wyT, wyB;
    float area;
    int   pad0, pad1, pad2;
};
static_assert(sizeof(BoxP) == 64, "BoxP size");

__device__ __forceinline__ int rfl_i(int x) {
    return __builtin_amdgcn_readfirstlane(x);
}
__device__ __forceinline__ float rfl_f(float x) {
    return __builtin_bit_cast(float, __builtin_amdgcn_readfirstlane(__builtin_bit_cast(int, x)));
}

// ---------------- Kernel 1: project grid corners to normalized coords ----------------
__global__ void k_project(const float* __restrict__ ks,
                          const float* __restrict__ imu2cs,
                          const float* __restrict__ post_rots,
                          const float* __restrict__ post_trans,
                          const float* __restrict__ undists,
                          const float* __restrict__ grid,
                          float2* __restrict__ ncbuf)
{
    const int n   = blockIdx.y;
    const int idx = blockIdx.x * blockDim.x + threadIdx.x;
    const int per = NY * GDIM * GDIM;
    if (idx >= per) return;
    const int ny  = idx / (GDIM * GDIM);
    const int rem = idx % (GDIM * GDIM);
    const int gz  = rem / GDIM;
    const int gx  = rem % GDIM;

    const float* k  = ks         + n * 9;
    const float* m  = imu2cs     + n * 12;
    const float* pr = post_rots  + n * 9;
    const float* pt = post_trans + n * 3;
    const float* D  = undists    + n * 7;

    float cal[12];
    #pragma unroll
    for (int i = 0; i < 3; ++i)
        #pragma unroll
        for (int j = 0; j < 4; ++j)
            cal[i*4+j] = k[i*3+0]*m[0*4+j] + k[i*3+1]*m[1*4+j] + k[i*3+2]*m[2*4+j];

    const float vx = grid[(gz*GDIM + gx)*3 + 0];
    const float vy = 2.0f - (float)ny;               // ys = -arange(0,4)+2
    const float vz = grid[(gz*GDIM + gx)*3 + 2];

    const float hx = cal[0]*vx + cal[1]*vy + cal[2]*vz  + cal[3];
    const float hy = cal[4]*vx + cal[5]*vy + cal[6]*vz  + cal[7];
    const float hz = cal[8]*vx + cal[9]*vy + cal[10]*vz + cal[11];

    const float fl = (hz > 0.0f) ? 1.0f : 0.0f;
    const float px = (hx * fl) / hz;
    const float py = (hy * fl) / hz;

    const float fx = k[0], fy = k[4], cx = k[2], cy = k[5];
    const float x = (px - cx) / fx;
    const float y = (py - cy) / fy;

    float xd, yd;
    if (D[6] == 1.0f) {
        const float r  = sqrtf(x*x + y*y);
        const float th = atanf(r);
        const float t2 = th * th;
        const float t4 = t2 * t2;
        const float rad = th * (1.0f + D[0]*t2 + D[1]*t4 + D[2]*(t2*t4) + D[5]*(t4*t4)) / r;
        xd = x * rad * fx + cx;
        yd = y * rad * fy + cy;
    } else {
        const float k1 = D[0], k2 = D[1], k3 = D[2], p1 = D[3], p2 = D[4];
        const float r2 = x*x + y*y;
        const float poly = 1.0f + k1*r2 + k2*r2*r2 + k3*r2*r2*r2;
        const float xdd = x*poly + (2.0f*p1*x*y + p2*(r2 + 2.0f*x*x));
        const float ydd = y*poly + (p1*(r2 + 2.0f*y*y) + 2.0f*p2*x*y);
        xd = xdd * fx + cx;
        yd = ydd * fy + cy;
    }
    xd *= fl; yd *= fl;

    const float qx = pr[0]*xd + pr[1]*yd + pt[0];
    const float qy = pr[3]*xd + pr[4]*yd + pt[1];
    const float ncx = fminf(fmaxf(2.0f*qx - 1.0f, -1.0f), 1.0f);
    const float ncy = fminf(fmaxf(2.0f*qy - 1.0f, -1.0f), 1.0f);
    ncbuf[((n*NY + ny)*GDIM + gz)*GDIM + gx] = make_float2(ncx, ncy);
}

// ---------------- Kernel 2a: row cumsum (axis=-1) + transpose to channel-last ----------------
// Segmented scan: 4 segments of 44 along w; all 256 threads active; critical path
// ~44 register adds instead of a 176-step LDS-dependent chain.
__global__ __launch_bounds__(256) void k_rowcum(const float* __restrict__ feat,
                                                float* __restrict__ integ)
{
    __shared__ float T[WF * 65];      // [w][c], stride 65: conflict-free
    __shared__ float S[4][C_CH];      // per-segment totals
    __shared__ float OFF[4][C_CH];    // exclusive segment offsets
    const int h   = blockIdx.x;
    const int n   = blockIdx.y;
    const int tid = threadIdx.x;

    for (int idx = tid; idx < C_CH * WF; idx += 256) {
        const int cc = idx / WF;
        const int w  = idx % WF;
        T[w*65 + cc] = feat[((size_t)(n*C_CH + cc)*HF + h)*WF + w];
    }
    __syncthreads();
    {
        const int cc = tid & 63, seg = tid >> 6;
        const int w0 = seg * 44;
        float run = 0.0f;
        #pragma unroll
        for (int i = 0; i < 44; ++i) {
            run += T[(w0 + i)*65 + cc];
            T[(w0 + i)*65 + cc] = run;
        }
        S[seg][cc] = run;
    }
    __syncthreads();
    {
        const int cc = tid & 63, seg = tid >> 6;
        float off = 0.0f;
        #pragma unroll
        for (int s = 0; s < 3; ++s)
            if (s < seg) off += S[s][cc];
        OFF[seg][cc] = off;
    }
    __syncthreads();
    float* outp = integ + (size_t)(n*HF + h) * (WF * C_CH);
    for (int idx = tid; idx < WF * C_CH; idx += 256) {
        const int w  = idx >> 6;
        const int cc = idx & 63;
        outp[idx] = T[w*65 + cc] + OFF[w/44][cc];   // [n][h][w][c], coalesced
    }
}

// ---------------- Kernel 2b: column cumsum (axis=-2), in place, channel-last ----------------
__global__ void k_colcum(float* __restrict__ integ)
{
    const int t = blockIdx.x * blockDim.x + threadIdx.x;
    const int n = blockIdx.y;
    if (t >= WF * C_CH) return;
    float* p = integ + (size_t)n * HF * WF * C_CH + t;
    float run = 0.0f;
    #pragma unroll
    for (int h = 0; h < HF; ++h) {
        run += p[(size_t)h * (WF * C_CH)];
        p[(size_t)h * (WF * C_CH)] = run;
    }
}

// ---------------- Kernel 3: bbox + bilinear params per (cam, nh, p) ----------------
__global__ void k_boxparams(const float2* __restrict__ ncbuf, BoxP* __restrict__ bp)
{
    const int idx = blockIdx.x * blockDim.x + threadIdx.x;
    if (idx >= NCAM * NH * NP) return;
    const int n  = idx / (NH * NP);
    const int r  = idx % (NH * NP);
    const int nh = r / NP;
    const int p  = r % NP;
    const int d  = p / WDIM;
    const int wd = p % WDIM;

    float left = 1e30f, right = -1e30f, top = 1e30f, bot = -1e30f;
    #pragma unroll
    for (int a = 0; a < 2; ++a)
        #pragma unroll
        for (int b = 0; b < 2; ++b)
            #pragma unroll
            for (int cc = 0; cc < 2; ++cc) {
                const float2 v = ncbuf[((n*NY + nh + a)*GDIM + d + b)*GDIM + wd + cc];
                left  = fminf(left,  v.x);  right = fmaxf(right, v.x);
                top   = fminf(top,   v.y);  bot   = fmaxf(bot,   v.y);
            }

    const float area = (right - left) * (bot - top) * (float)HF * (float)WF * 0.25f + 1e-6f;

    const float xLp = fminf(fmaxf((left  + 1.0f) * 0.5f * (float)(WF-1), 0.0f), (float)(WF-1));
    const float xRp = fminf(fmaxf((right + 1.0f) * 0.5f * (float)(WF-1), 0.0f), (float)(WF-1));
    const float yTp = fminf(fmaxf((top   + 1.0f) * 0.5f * (float)(HF-1), 0.0f), (float)(HF-1));
    const float yBp = fminf(fmaxf((bot   + 1.0f) * 0.5f * (float)(HF-1), 0.0f), (float)(HF-1));
    const float xL0 = floorf(xLp), xR0 = floorf(xRp), yT0 = floorf(yTp), yB0 = floorf(yBp);

    const int ixL0 = (int)xL0, ixR0 = (int)xR0, iyT0 = (int)yT0, iyB0 = (int)yB0;
    const int ixL1 = min(ixL0 + 1, WF-1), ixR1 = min(ixR0 + 1, WF-1);
    const int iyT1 = min(iyT0 + 1, HF-1), iyB1 = min(iyB0 + 1, HF-1);

    BoxP o;
    o.r0 = iyT0 * (WF*C_CH*4); o.r1 = iyT1 * (WF*C_CH*4);
    o.r2 = iyB0 * (WF*C_CH*4); o.r3 = iyB1 * (WF*C_CH*4);
    o.c0 = ixL0 * (C_CH*4);    o.c1 = ixL1 * (C_CH*4);
    o.c2 = ixR0 * (C_CH*4);    o.c3 = ixR1 * (C_CH*4);
    o.wxL = xLp - xL0; o.wxR = xRp - xR0; o.wyT = yTp - yT0; o.wyB = yBp - yB0;
    o.area = area; o.pad0 = 0; o.pad1 = 0; o.pad2 = 0;
    bp[idx] = o;
}

// ---------------- Kernel 4: sample integral image, combine, max over cameras ----------------
// Wave per (nh,p), lane = channel. BoxP is wave-uniform (readfirstlane-forced) so
// box load + texel addressing run on the scalar pipe; gathers are coalesced 256B.
// Degenerate boxes (area<=EPS -> val==0) skip all 16 loads via a uniform branch.
__global__ __launch_bounds__(256) void k_sample(const float* __restrict__ integ,
                                                const BoxP* __restrict__ bp,
                                                float* __restrict__ out)
{
    __shared__ float sm[C_CH][17];
    const int nh   = blockIdx.y;
    const int p0   = blockIdx.x * 16;
    const int tid  = threadIdx.x;
    const int wave = __builtin_amdgcn_readfirstlane(tid >> 6);
    const int c    = tid & 63;

    #pragma unroll 1
    for (int j = 0; j < 4; ++j) {
        const int pj = p0 + wave*4 + j;
        float vmax = -3.402823466e38f;
        #pragma unroll 1
        for (int n = 0; n < NCAM; ++n) {
            const BoxP* bpp = &bp[(n*NH + nh)*NP + pj];
            const float area = rfl_f(bpp->area);
            if (!(area > 1e-6f)) {          // reference: vox * (area > EPS) == 0
                vmax = fmaxf(vmax, 0.0f);
                continue;
            }
            const int r0 = rfl_i(bpp->r0), r1 = rfl_i(bpp->r1);
            const int r2 = rfl_i(bpp->r2), r3 = rfl_i(bpp->r3);
            const int c0 = rfl_i(bpp->c0), c1 = rfl_i(bpp->c1);
            const int c2 = rfl_i(bpp->c2), c3 = rfl_i(bpp->c3);
            const float wxL = rfl_f(bpp->wxL), wxR = rfl_f(bpp->wxR);
            const float wyT = rfl_f(bpp->wyT), wyB = rfl_f(bpp->wyB);

            const char* base = (const char*)integ + (size_t)n * (HF*WF*C_CH*4);
            auto LD = [&](int ro, int co) -> float {
                return ((const float*)(base + (size_t)(ro + co)))[c];
            };
            // 16 texel loads (issued up-front, independent)
            const float t0L0 = LD(r0,c0), t0L1 = LD(r0,c1), t0R0 = LD(r0,c2), t0R1 = LD(r0,c3);
            const float t1L0 = LD(r1,c0), t1L1 = LD(r1,c1), t1R0 = LD(r1,c2), t1R1 = LD(r1,c3);
            const float b0L0 = LD(r2,c0), b0L1 = LD(r2,c1), b0R0 = LD(r2,c2), b0R1 = LD(r2,c3);
            const float b1L0 = LD(r3,c0), b1L1 = LD(r3,c1), b1R0 = LD(r3,c2), b1R1 = LD(r3,c3);

            // separable bilinear: tl+br-tr-bl = lerp_y(A-B | top) + lerp_y(B-A | bot)
            const float A0 = fmaf(wxL, t0L1 - t0L0, t0L0);
            const float B0 = fmaf(wxR, t0R1 - t0R0, t0R0);
            const float A1 = fmaf(wxL, t1L1 - t1L0, t1L0);
            const float B1 = fmaf(wxR, t1R1 - t1R0, t1R0);
            const float A2 = fmaf(wxL, b0L1 - b0L0, b0L0);
            const float B2 = fmaf(wxR, b0R1 - b0R0, b0R0);
            const float A3 = fmaf(wxL, b1L1 - b1L0, b1L0);
            const float B3 = fmaf(wxR, b1R1 - b1R0, b1R0);
            const float d0 = A0 - B0, d1 = A1 - B1;
            const float e0 = B2 - A2, e1 = B3 - A3;
            const float s = fmaf(wyT, d1 - d0, d0) + fmaf(wyB, e1 - e0, e0);
            const float val = s * __builtin_amdgcn_rcpf(area);
            vmax = fmaxf(vmax, val);
        }
        sm[c][wave*4 + j] = vmax;
    }
    __syncthreads();
    for (int idx = tid; idx < C_CH * 16; idx += 256) {
        const int cc = idx >> 4;
        const int jj = idx & 15;
        out[(size_t)(cc*NH + nh)*NP + p0 + jj] = sm[cc][jj];
    }
}

extern "C" void kernel_launch(void* const* d_in, const int* in_sizes, int n_in,
                              void* d_out, int out_size, void* d_ws, size_t ws_size,
                              hipStream_t stream)
{
    const float* feats      = (const float*)d_in[0];  // [1,6,64,64,176]
    const float* ks         = (const float*)d_in[1];  // [1,6,3,3]
    const float* imu2cs     = (const float*)d_in[2];  // [1,6,3,4]
    const float* post_rots  = (const float*)d_in[3];  // [1,6,3,3]
    const float* post_trans = (const float*)d_in[4];  // [1,6,3]
    const float* undists    = (const float*)d_in[5];  // [1,6,7]
    const float* grid       = (const float*)d_in[6];  // [1,129,129,3]
    float* out = (float*)d_out;                       // [1,192,128,128]

    char* ws = (char*)d_ws;
    size_t off = 0;
    float2* ncbuf = (float2*)(ws + off);
    off += sizeof(float2) * NCAM * NY * GDIM * GDIM;
    off = (off + 255) & ~(size_t)255;
    float* integ = (float*)(ws + off);
    off += sizeof(float) * NCAM * HF * WF * C_CH;
    off = (off + 255) & ~(size_t)255;
    BoxP* bp = (BoxP*)(ws + off);
    off += sizeof(BoxP) * NCAM * NH * NP;
    (void)ws_size; (void)in_sizes; (void)n_in; (void)out_size;

    dim3 g1((NY*GDIM*GDIM + 255)/256, NCAM);
    k_project<<<g1, 256, 0, stream>>>(ks, imu2cs, post_rots, post_trans, undists, grid, ncbuf);

    dim3 g2a(HF, NCAM);
    k_rowcum<<<g2a, 256, 0, stream>>>(feats, integ);

    dim3 g2b((WF*C_CH + 255)/256, NCAM);
    k_colcum<<<g2b, 256, 0, stream>>>(integ);

    dim3 g3((NCAM*NH*NP + 255)/256);
    k_boxparams<<<g3, 256, 0, stream>>>(ncbuf, bp);

    dim3 g4(NP/16, NH);
    k_sample<<<g4, 256, 0, stream>>>(integ, bp, out);
}

// Round 3
// 157.957 us; speedup vs baseline: 1.1201x; 1.0190x over previous
//
#include <hip/hip_runtime.h>
#include <math.h>

#define NCAM 6
#define C_CH 64
#define HF   64
#define WF   176
#define GDIM 129
#define NY   4
#define NH   3
#define DD   128
#define WDIM 128
#define NP   (DD*WDIM)

// BoxP: 4 precombined byte offsets into the quad buffer (corner sample points),
// 4 lerp weights, gated area. 48B, scalar-loaded once per (cam,voxel) per wave.
struct alignas(16) BoxP {
    int   oTL, oTR, oBL, oBR;   // byte offsets of quad texels (y*WF+x)*C_CH*16
    float wxL, wxR, wyT, wyB;
    float area;
    int   pad0, pad1, pad2;
};
static_assert(sizeof(BoxP) == 48, "BoxP size");

__device__ __forceinline__ int rfl_i(int x) {
    return __builtin_amdgcn_readfirstlane(x);
}
__device__ __forceinline__ float rfl_f(float x) {
    return __builtin_bit_cast(float, __builtin_amdgcn_readfirstlane(__builtin_bit_cast(int, x)));
}

// ---------------- Kernel 1: project grid corners to normalized coords ----------------
__global__ void k_project(const float* __restrict__ ks,
                          const float* __restrict__ imu2cs,
                          const float* __restrict__ post_rots,
                          const float* __restrict__ post_trans,
                          const float* __restrict__ undists,
                          const float* __restrict__ grid,
                          float2* __restrict__ ncbuf)
{
    const int n   = blockIdx.y;
    const int idx = blockIdx.x * blockDim.x + threadIdx.x;
    const int per = NY * GDIM * GDIM;
    if (idx >= per) return;
    const int ny  = idx / (GDIM * GDIM);
    const int rem = idx % (GDIM * GDIM);
    const int gz  = rem / GDIM;
    const int gx  = rem % GDIM;

    const float* k  = ks         + n * 9;
    const float* m  = imu2cs     + n * 12;
    const float* pr = post_rots  + n * 9;
    const float* pt = post_trans + n * 3;
    const float* D  = undists    + n * 7;

    float cal[12];
    #pragma unroll
    for (int i = 0; i < 3; ++i)
        #pragma unroll
        for (int j = 0; j < 4; ++j)
            cal[i*4+j] = k[i*3+0]*m[0*4+j] + k[i*3+1]*m[1*4+j] + k[i*3+2]*m[2*4+j];

    const float vx = grid[(gz*GDIM + gx)*3 + 0];
    const float vy = 2.0f - (float)ny;               // ys = -arange(0,4)+2
    const float vz = grid[(gz*GDIM + gx)*3 + 2];

    const float hx = cal[0]*vx + cal[1]*vy + cal[2]*vz  + cal[3];
    const float hy = cal[4]*vx + cal[5]*vy + cal[6]*vz  + cal[7];
    const float hz = cal[8]*vx + cal[9]*vy + cal[10]*vz + cal[11];

    const float fl = (hz > 0.0f) ? 1.0f : 0.0f;
    const float px = (hx * fl) / hz;
    const float py = (hy * fl) / hz;

    const float fx = k[0], fy = k[4], cx = k[2], cy = k[5];
    const float x = (px - cx) / fx;
    const float y = (py - cy) / fy;

    float xd, yd;
    if (D[6] == 1.0f) {
        const float r  = sqrtf(x*x + y*y);
        const float th = atanf(r);
        const float t2 = th * th;
        const float t4 = t2 * t2;
        const float rad = th * (1.0f + D[0]*t2 + D[1]*t4 + D[2]*(t2*t4) + D[5]*(t4*t4)) / r;
        xd = x * rad * fx + cx;
        yd = y * rad * fy + cy;
    } else {
        const float k1 = D[0], k2 = D[1], k3 = D[2], p1 = D[3], p2 = D[4];
        const float r2 = x*x + y*y;
        const float poly = 1.0f + k1*r2 + k2*r2*r2 + k3*r2*r2*r2;
        const float xdd = x*poly + (2.0f*p1*x*y + p2*(r2 + 2.0f*x*x));
        const float ydd = y*poly + (p1*(r2 + 2.0f*y*y) + 2.0f*p2*x*y);
        xd = xdd * fx + cx;
        yd = ydd * fy + cy;
    }
    xd *= fl; yd *= fl;

    const float qx = pr[0]*xd + pr[1]*yd + pt[0];
    const float qy = pr[3]*xd + pr[4]*yd + pt[1];
    const float ncx = fminf(fmaxf(2.0f*qx - 1.0f, -1.0f), 1.0f);
    const float ncy = fminf(fmaxf(2.0f*qy - 1.0f, -1.0f), 1.0f);
    ncbuf[((n*NY + ny)*GDIM + gz)*GDIM + gx] = make_float2(ncx, ncy);
}

// ---------------- Kernel 2a: row cumsum (axis=-1) -> channel-last rowsum ----------------
__global__ __launch_bounds__(256) void k_rowcum(const float* __restrict__ feat,
                                                float* __restrict__ rowsum)
{
    __shared__ float T[WF * 65];
    __shared__ float S[4][C_CH];
    __shared__ float OFF[4][C_CH];
    const int h   = blockIdx.x;
    const int n   = blockIdx.y;
    const int tid = threadIdx.x;

    for (int idx = tid; idx < C_CH * WF; idx += 256) {
        const int cc = idx / WF;
        const int w  = idx % WF;
        T[w*65 + cc] = feat[((size_t)(n*C_CH + cc)*HF + h)*WF + w];
    }
    __syncthreads();
    {
        const int cc = tid & 63, seg = tid >> 6;
        const int w0 = seg * 44;
        float run = 0.0f;
        #pragma unroll
        for (int i = 0; i < 44; ++i) {
            run += T[(w0 + i)*65 + cc];
            T[(w0 + i)*65 + cc] = run;
        }
        S[seg][cc] = run;
    }
    __syncthreads();
    {
        const int cc = tid & 63, seg = tid >> 6;
        float off = 0.0f;
        #pragma unroll
        for (int s = 0; s < 3; ++s)
            if (s < seg) off += S[s][cc];
        OFF[seg][cc] = off;
    }
    __syncthreads();
    float* outp = rowsum + (size_t)(n*HF + h) * (WF * C_CH);
    for (int idx = tid; idx < WF * C_CH; idx += 256) {
        const int w  = idx >> 6;
        const int cc = idx & 63;
        outp[idx] = T[w*65 + cc] + OFF[w/44][cc];
    }
}

// ---------------- Kernel 2b: column cumsum + quad-texel emission ----------------
// Block per (n, x). Scans columns x and x+1 over h (4 segments of 16 in registers,
// LDS offset fix-up), then emits qbuf[n][h][x][c] = (I[h][x], I[h][x1], I[h1][x], I[h1][x1])
// with x1/h1 clamp baked in. One coalesced dwordx4 store per (h,c).
__global__ __launch_bounds__(256) void k_quadcol(const float* __restrict__ rowsum,
                                                 float4* __restrict__ qbuf)
{
    __shared__ float A[HF][C_CH];    // scanned column x
    __shared__ float Bb[HF][C_CH];   // scanned column x+1 (clamped)
    __shared__ float tA[4][C_CH], tB[4][C_CH];
    const int x  = blockIdx.x;
    const int n  = blockIdx.y;
    const int x1 = min(x + 1, WF - 1);
    const int c  = threadIdx.x & 63;
    const int hq = threadIdx.x >> 6;

    const float* base0 = rowsum + (size_t)n*HF*WF*C_CH + (size_t)x  * C_CH + c;
    const float* base1 = rowsum + (size_t)n*HF*WF*C_CH + (size_t)x1 * C_CH + c;
    float run0 = 0.0f, run1 = 0.0f;
    #pragma unroll
    for (int i = 0; i < 16; ++i) {
        const int h = hq*16 + i;
        run0 += base0[(size_t)h * (WF*C_CH)];
        run1 += base1[(size_t)h * (WF*C_CH)];
        A[h][c]  = run0;
        Bb[h][c] = run1;
    }
    tA[hq][c] = run0;
    tB[hq][c] = run1;
    __syncthreads();
    {
        float offA = 0.0f, offB = 0.0f;
        #pragma unroll
        for (int s = 0; s < 3; ++s)
            if (s < hq) { offA += tA[s][c]; offB += tB[s][c]; }
        #pragma unroll
        for (int i = 0; i < 16; ++i) {
            const int h = hq*16 + i;
            A[h][c]  += offA;
            Bb[h][c] += offB;
        }
    }
    __syncthreads();
    float4* qb = qbuf + ((size_t)n*HF*WF + x) * C_CH + c;
    #pragma unroll
    for (int i = 0; i < 16; ++i) {
        const int h  = hq*16 + i;
        const int hn = min(h + 1, HF - 1);
        float4 q;
        q.x = A[h][c];  q.y = Bb[h][c];
        q.z = A[hn][c]; q.w = Bb[hn][c];
        qb[(size_t)h * (WF*C_CH)] = q;
    }
}

// ---------------- Kernel 3: bbox + quad offsets per (cam, nh, p) ----------------
__global__ void k_boxparams(const float2* __restrict__ ncbuf, BoxP* __restrict__ bp)
{
    const int idx = blockIdx.x * blockDim.x + threadIdx.x;
    if (idx >= NCAM * NH * NP) return;
    const int n  = idx / (NH * NP);
    const int r  = idx % (NH * NP);
    const int nh = r / NP;
    const int p  = r % NP;
    const int d  = p / WDIM;
    const int wd = p % WDIM;

    float left = 1e30f, right = -1e30f, top = 1e30f, bot = -1e30f;
    #pragma unroll
    for (int a = 0; a < 2; ++a)
        #pragma unroll
        for (int b = 0; b < 2; ++b)
            #pragma unroll
            for (int cc = 0; cc < 2; ++cc) {
                const float2 v = ncbuf[((n*NY + nh + a)*GDIM + d + b)*GDIM + wd + cc];
                left  = fminf(left,  v.x);  right = fmaxf(right, v.x);
                top   = fminf(top,   v.y);  bot   = fmaxf(bot,   v.y);
            }

    const float area = (right - left) * (bot - top) * (float)HF * (float)WF * 0.25f + 1e-6f;

    const float xLp = fminf(fmaxf((left  + 1.0f) * 0.5f * (float)(WF-1), 0.0f), (float)(WF-1));
    const float xRp = fminf(fmaxf((right + 1.0f) * 0.5f * (float)(WF-1), 0.0f), (float)(WF-1));
    const float yTp = fminf(fmaxf((top   + 1.0f) * 0.5f * (float)(HF-1), 0.0f), (float)(HF-1));
    const float yBp = fminf(fmaxf((bot   + 1.0f) * 0.5f * (float)(HF-1), 0.0f), (float)(HF-1));
    const float xL0 = floorf(xLp), xR0 = floorf(xRp), yT0 = floorf(yTp), yB0 = floorf(yBp);

    const int rT = (int)yT0 * (WF*C_CH*16);
    const int rB = (int)yB0 * (WF*C_CH*16);
    const int cL = (int)xL0 * (C_CH*16);
    const int cR = (int)xR0 * (C_CH*16);

    BoxP o;
    o.oTL = rT + cL; o.oTR = rT + cR; o.oBL = rB + cL; o.oBR = rB + cR;
    o.wxL = xLp - xL0; o.wxR = xRp - xR0; o.wyT = yTp - yT0; o.wyB = yBp - yB0;
    o.area = area; o.pad0 = 0; o.pad1 = 0; o.pad2 = 0;
    bp[idx] = o;
}

// ---------------- Kernel 4: sample quad texels, combine, max over cameras ----------------
// 32 voxels/block -> 1536 blocks (all co-resident, no tail). Wave per 8 voxels,
// lane = channel. 4 dwordx4 loads (1KiB/wave each) replace 16 dword gathers.
__global__ __launch_bounds__(256) void k_sample(const float4* __restrict__ qbuf,
                                                const BoxP* __restrict__ bp,
                                                float* __restrict__ out)
{
    __shared__ float sm[C_CH][33];
    const int nh   = blockIdx.y;
    const int p0   = blockIdx.x * 32;
    const int tid  = threadIdx.x;
    const int wave = __builtin_amdgcn_readfirstlane(tid >> 6);
    const int c    = tid & 63;

    #pragma unroll 1
    for (int j = 0; j < 8; ++j) {
        const int pj = p0 + wave*8 + j;
        float vmax = -3.402823466e38f;
        #pragma unroll 1
        for (int n = 0; n < NCAM; ++n) {
            const BoxP* bpp = &bp[(n*NH + nh)*NP + pj];
            const float area = rfl_f(bpp->area);
            if (!(area > 1e-6f)) {          // reference: vox * (area > EPS) == 0
                vmax = fmaxf(vmax, 0.0f);
                continue;
            }
            const int oTL = rfl_i(bpp->oTL), oTR = rfl_i(bpp->oTR);
            const int oBL = rfl_i(bpp->oBL), oBR = rfl_i(bpp->oBR);
            const float wxL = rfl_f(bpp->wxL), wxR = rfl_f(bpp->wxR);
            const float wyT = rfl_f(bpp->wyT), wyB = rfl_f(bpp->wyB);

            const char* qb = (const char*)qbuf + (size_t)n * ((size_t)HF*WF*C_CH*16);
            auto LDQ = [&](int off) -> float4 {
                return ((const float4*)(qb + (size_t)off))[c];
            };
            const float4 qTL = LDQ(oTL);
            const float4 qTR = LDQ(oTR);
            const float4 qBL = LDQ(oBL);
            const float4 qBR = LDQ(oBR);

            auto BIL = [&](const float4& q, float wx, float wy) -> float {
                const float m0 = fmaf(wx, q.y - q.x, q.x);
                const float m1 = fmaf(wx, q.w - q.z, q.z);
                return fmaf(wy, m1 - m0, m0);
            };
            const float tl = BIL(qTL, wxL, wyT);
            const float tr = BIL(qTR, wxR, wyT);
            const float bl = BIL(qBL, wxL, wyB);
            const float br = BIL(qBR, wxR, wyB);
            const float s  = (tl + br) - (tr + bl);
            vmax = fmaxf(vmax, s * __builtin_amdgcn_rcpf(area));
        }
        sm[c][wave*8 + j] = vmax;
    }
    __syncthreads();
    for (int idx = tid; idx < C_CH * 32; idx += 256) {
        const int cc = idx >> 5;
        const int jj = idx & 31;
        out[(size_t)(cc*NH + nh)*NP + p0 + jj] = sm[cc][jj];
    }
}

extern "C" void kernel_launch(void* const* d_in, const int* in_sizes, int n_in,
                              void* d_out, int out_size, void* d_ws, size_t ws_size,
                              hipStream_t stream)
{
    const float* feats      = (const float*)d_in[0];  // [1,6,64,64,176]
    const float* ks         = (const float*)d_in[1];  // [1,6,3,3]
    const float* imu2cs     = (const float*)d_in[2];  // [1,6,3,4]
    const float* post_rots  = (const float*)d_in[3];  // [1,6,3,3]
    const float* post_trans = (const float*)d_in[4];  // [1,6,3]
    const float* undists    = (const float*)d_in[5];  // [1,6,7]
    const float* grid       = (const float*)d_in[6];  // [1,129,129,3]
    float* out = (float*)d_out;                       // [1,192,128,128]

    char* ws = (char*)d_ws;
    size_t off = 0;
    float2* ncbuf = (float2*)(ws + off);
    off += sizeof(float2) * NCAM * NY * GDIM * GDIM;
    off = (off + 255) & ~(size_t)255;
    float* rowsum = (float*)(ws + off);
    off += sizeof(float) * NCAM * HF * WF * C_CH;
    off = (off + 255) & ~(size_t)255;
    float4* qbuf = (float4*)(ws + off);
    off += sizeof(float4) * (size_t)NCAM * HF * WF * C_CH;
    off = (off + 255) & ~(size_t)255;
    BoxP* bp = (BoxP*)(ws + off);
    off += sizeof(BoxP) * NCAM * NH * NP;
    (void)ws_size; (void)in_sizes; (void)n_in; (void)out_size;

    dim3 g1((NY*GDIM*GDIM + 255)/256, NCAM);
    k_project<<<g1, 256, 0, stream>>>(ks, imu2cs, post_rots, post_trans, undists, grid, ncbuf);

    dim3 g2a(HF, NCAM);
    k_rowcum<<<g2a, 256, 0, stream>>>(feats, rowsum);

    dim3 g2b(WF, NCAM);
    k_quadcol<<<g2b, 256, 0, stream>>>(rowsum, qbuf);

    dim3 g3((NCAM*NH*NP + 255)/256);
    k_boxparams<<<g3, 256, 0, stream>>>(ncbuf, bp);

    dim3 g4(NP/32, NH);
    k_sample<<<g4, 256, 0, stream>>>(qbuf, bp, out);
}